// Round 1
// baseline (408.586 us; speedup 1.0000x reference)
//
#include <hip/hip_runtime.h>

#define Bn   4
#define CINc 64
#define COUTc 64
#define Hn   128
#define Wn   128
#define KKc  9
#define NOFF 18

// ---------------------------------------------------------------------------
// Kernel W: transpose w_def (o,c,k) -> wt (k,c,o) for coalesced LDS staging
// ---------------------------------------------------------------------------
__global__ void transpose_wdef(const float* __restrict__ w_def,
                               float* __restrict__ wt) {
    int idx = blockIdx.x * 256 + threadIdx.x;       // 64*64*9 = 36864 total
    if (idx >= COUTc * CINc * KKc) return;
    int k = idx % KKc;
    int c = (idx / KKc) % CINc;
    int o = idx / (KKc * CINc);
    wt[(k * CINc + c) * COUTc + o] = w_def[idx];
}

// ---------------------------------------------------------------------------
// Kernel A: offset conv  off[b,oc,h,w] = sum_c sum_3x3 x * w_off  + b_off
// grid: 4*18*64 blocks, 256 threads (2 rows x 128 cols)
// ---------------------------------------------------------------------------
__global__ __launch_bounds__(256) void offset_conv(
        const float* __restrict__ x, const float* __restrict__ w_off,
        const float* __restrict__ b_off, float* __restrict__ off) {
    int bid = blockIdx.x;
    int h2  = bid % (Hn / 2);
    int oc  = (bid / (Hn / 2)) % NOFF;
    int b   = bid / (NOFF * (Hn / 2));
    int w   = threadIdx.x & (Wn - 1);
    int h   = h2 * 2 + (threadIdx.x >> 7);

    const float* xb = x + (size_t)b * CINc * Hn * Wn;
    const float* wo = w_off + oc * CINc * 9;   // uniform across block -> s_load
    float acc = b_off[oc];

    for (int c = 0; c < CINc; ++c) {
        const float* xc = xb + c * Hn * Wn;
        const float* wc = wo + c * 9;
        #pragma unroll
        for (int ky = 0; ky < 3; ++ky) {
            int y = h - 1 + ky;
            if (y < 0 || y >= Hn) continue;
            const float* xr = xc + y * Wn;
            #pragma unroll
            for (int kx = 0; kx < 3; ++kx) {
                int xcol = w - 1 + kx;
                if (xcol < 0 || xcol >= Wn) continue;
                acc += wc[ky * 3 + kx] * xr[xcol];
            }
        }
    }
    off[(((size_t)b * NOFF + oc) * Hn + h) * Wn + w] = acc;
}

// ---------------------------------------------------------------------------
// Kernel B: bilinear sample + einsum.
// block = (b, h, 64-wide pixel tile), 256 threads.
//   phase 1: bilinear corner addresses + validity-masked weights -> LDS
//   per k:   stage sampled[c][p] (gather) and wk[c][o] -> LDS,
//            4x4 register-tile fp32 outer product (o-tile x p-tile).
// ---------------------------------------------------------------------------
__global__ __launch_bounds__(256) void deform_main(
        const float* __restrict__ x, const float* __restrict__ off,
        const float* __restrict__ wt, float* __restrict__ out) {
    __shared__ float s_wts[KKc][64][4];     // masked bilinear weights
    __shared__ int   s_addr[KKc][64][4];    // clipped flat y*W+x per corner
    __shared__ float s_samp[CINc][68];      // sampled[c][p] for current k
    __shared__ float s_wk[CINc][68];        // w_def[k][c][o] for current k

    int gid = blockIdx.x;                   // 4*128*2 = 1024 blocks
    int wt2 = gid & 1;
    int h   = (gid >> 1) & (Hn - 1);
    int b   = gid >> 8;
    int w0  = wt2 * 64;
    int tid = threadIdx.x;

    // ---- phase 1: positions / weights for the 9*64 (k,p) pairs ----
    for (int j = tid; j < KKc * 64; j += 256) {
        int k = j >> 6, p = j & 63;
        float dy = off[(((size_t)b * NOFF + 2 * k) * Hn + h) * Wn + w0 + p];
        float dx = off[(((size_t)b * NOFF + 2 * k + 1) * Hn + h) * Wn + w0 + p];
        float py = (float)(h - 1 + k / 3) + dy;
        float px = (float)(w0 + p - 1 + k % 3) + dx;
        float y0f = floorf(py), x0f = floorf(px);
        float fy = py - y0f, fx = px - x0f;
        int y0 = (int)y0f, x0 = (int)x0f;
        int y1 = y0 + 1, x1 = x0 + 1;
        bool vy0 = (y0 >= 0) & (y0 < Hn);
        bool vy1 = (y1 >= 0) & (y1 < Hn);
        bool vx0 = (x0 >= 0) & (x0 < Wn);
        bool vx1 = (x1 >= 0) & (x1 < Wn);
        float wy0 = 1.f - fy, wx0 = 1.f - fx;
        s_wts[k][p][0] = (vy0 && vx0) ? wy0 * wx0 : 0.f;
        s_wts[k][p][1] = (vy0 && vx1) ? wy0 * fx : 0.f;
        s_wts[k][p][2] = (vy1 && vx0) ? fy * wx0 : 0.f;
        s_wts[k][p][3] = (vy1 && vx1) ? fy * fx : 0.f;
        int yc0 = min(max(y0, 0), Hn - 1), yc1 = min(max(y1, 0), Hn - 1);
        int xc0 = min(max(x0, 0), Wn - 1), xc1 = min(max(x1, 0), Wn - 1);
        s_addr[k][p][0] = yc0 * Wn + xc0;
        s_addr[k][p][1] = yc0 * Wn + xc1;
        s_addr[k][p][2] = yc1 * Wn + xc0;
        s_addr[k][p][3] = yc1 * Wn + xc1;
    }

    float acc[4][4] = {{0.f}};
    int p_g = tid & 63;           // staging: pixel
    int c_g = (tid >> 6) * 16;    // staging: channel base (16 channels each)
    int o0  = (tid >> 4) * 4;     // compute: o-tile
    int p0  = (tid & 15) * 4;     // compute: p-tile
    const float* xb = x + (size_t)b * CINc * Hn * Wn;

    for (int k = 0; k < KKc; ++k) {
        __syncthreads();   // phase1 done (k=0) / prev compute reads done (k>0)

        // ---- stage wk[c][o] (coalesced float4 from transposed w_def) ----
        const float* wk_src = wt + k * CINc * COUTc;
        #pragma unroll
        for (int i = 0; i < 4; ++i) {
            int idx = (i * 256 + tid) * 4;          // 0..4095, step 4
            int c = idx >> 6, o = idx & 63;
            float4 v = *(const float4*)(wk_src + idx);
            *(float4*)&s_wk[c][o] = v;
        }

        // ---- stage sampled[c][p] via bilinear gather ----
        int a0 = s_addr[k][p_g][0], a1 = s_addr[k][p_g][1];
        int a2 = s_addr[k][p_g][2], a3 = s_addr[k][p_g][3];
        float W0 = s_wts[k][p_g][0], W1 = s_wts[k][p_g][1];
        float W2 = s_wts[k][p_g][2], W3 = s_wts[k][p_g][3];
        #pragma unroll 4
        for (int i = 0; i < 16; ++i) {
            int c = c_g + i;
            const float* xc = xb + c * Hn * Wn;
            s_samp[c][p_g] = W0 * xc[a0] + W1 * xc[a1] + W2 * xc[a2] + W3 * xc[a3];
        }
        __syncthreads();

        // ---- 4x4 register-tile outer product over c ----
        #pragma unroll 8
        for (int c = 0; c < CINc; ++c) {
            float4 wv = *(float4*)&s_wk[c][o0];
            float4 sv = *(float4*)&s_samp[c][p0];
            float wa[4] = {wv.x, wv.y, wv.z, wv.w};
            float sa[4] = {sv.x, sv.y, sv.z, sv.w};
            #pragma unroll
            for (int i = 0; i < 4; ++i)
                #pragma unroll
                for (int j = 0; j < 4; ++j)
                    acc[i][j] += wa[i] * sa[j];
        }
    }

    // ---- write out: 4 rows of float4 ----
    #pragma unroll
    for (int i = 0; i < 4; ++i) {
        float4 v = make_float4(acc[i][0], acc[i][1], acc[i][2], acc[i][3]);
        *(float4*)(out + (((size_t)b * COUTc + o0 + i) * Hn + h) * Wn + w0 + p0) = v;
    }
}

// ---------------------------------------------------------------------------
extern "C" void kernel_launch(void* const* d_in, const int* in_sizes, int n_in,
                              void* d_out, int out_size, void* d_ws, size_t ws_size,
                              hipStream_t stream) {
    const float* x     = (const float*)d_in[0];
    const float* w_off = (const float*)d_in[1];
    const float* b_off = (const float*)d_in[2];
    const float* w_def = (const float*)d_in[3];
    float* out = (float*)d_out;

    float* off = (float*)d_ws;                                   // 4*18*128*128 fp32
    float* wtp = (float*)((char*)d_ws + (size_t)Bn * NOFF * Hn * Wn * 4);

    transpose_wdef<<<(COUTc * CINc * KKc + 255) / 256, 256, 0, stream>>>(w_def, wtp);
    offset_conv<<<Bn * NOFF * (Hn / 2), 256, 0, stream>>>(x, w_off, b_off, off);
    deform_main<<<Bn * Hn * (Wn / 64), 256, 0, stream>>>(x, off, wtp, out);
}

// Round 2
// 298.087 us; speedup vs baseline: 1.3707x; 1.3707x over previous
//
#include <hip/hip_runtime.h>

#define Bn   4
#define CINc 64
#define COUTc 64
#define Hn   128
#define Wn   128
#define KKc  9
#define NOFF 18

// ---------------------------------------------------------------------------
// Kernel W: transpose w_def (o,c,k) -> wt (k,c,o) for coalesced LDS staging
// ---------------------------------------------------------------------------
__global__ void transpose_wdef(const float* __restrict__ w_def,
                               float* __restrict__ wt) {
    int idx = blockIdx.x * 256 + threadIdx.x;       // 64*64*9 = 36864 total
    if (idx >= COUTc * CINc * KKc) return;
    int k = idx % KKc;
    int c = (idx / KKc) % CINc;
    int o = idx / (KKc * CINc);
    wt[(k * CINc + c) * COUTc + o] = w_def[idx];
}

// ---------------------------------------------------------------------------
// Kernel A v2: offset conv, LDS-tiled, weight-in-SGPR.
// block = (b, 2-row slab) -> 4*64 = 256 blocks, 256 threads, 1 pixel/thread,
// 18 accumulators/thread. x staged in 8-channel chunks [8][4 rows][132 cols]
// (zero-padded halo). Global loads for chunk k+1 issued AFTER the barrier,
// overlapped with chunk k's FMA block (barrier drains vmcnt, so issuing
// before it would serialize).
// ---------------------------------------------------------------------------
#define NCH 8          // channels per chunk
#define TW  132        // tile width: cols 0..131 = x -1..130 (need 0..129)
#define CHUNK_ELEMS (NCH * 4 * TW)   // 4224

__global__ __launch_bounds__(256) void offset_conv_v2(
        const float* __restrict__ x, const float* __restrict__ w_off,
        const float* __restrict__ b_off, float* __restrict__ off) {
    __shared__ float s_x[2][NCH][4][TW];

    int bid = blockIdx.x;            // 4 * 64
    int h0  = (bid & 63) * 2;
    int b   = bid >> 6;
    int tid = threadIdx.x;
    int w   = tid & 127;             // pixel col
    int ty  = tid >> 7;              // pixel row within slab (0/1)

    const float* xb = x + (size_t)b * CINc * Hn * Wn;

    float reg[17];
    float acc[NOFF];
    #pragma unroll
    for (int i = 0; i < NOFF; ++i) acc[i] = 0.f;

    // ---- load one chunk's elements global -> regs (zero-padded halo) ----
    auto stage_load = [&](int chunk) {
        #pragma unroll
        for (int i = 0; i < 17; ++i) {
            int idx = tid + i * 256;
            if (idx < CHUNK_ELEMS) {
                int c   = idx / (4 * TW);
                int rem = idx - c * (4 * TW);
                int r   = rem / TW;
                int col = rem - r * TW;
                int y   = h0 - 1 + r;
                int xg  = col - 1;
                float v = 0.f;
                if (y >= 0 && y < Hn && xg >= 0 && xg < Wn)
                    v = xb[((size_t)(chunk * NCH + c) * Hn + y) * Wn + xg];
                reg[i] = v;
            }
        }
    };
    auto stage_store = [&](int buf) {
        #pragma unroll
        for (int i = 0; i < 17; ++i) {
            int idx = tid + i * 256;
            if (idx < CHUNK_ELEMS) {
                int c   = idx / (4 * TW);
                int rem = idx - c * (4 * TW);
                int r   = rem / TW;
                int col = rem - r * TW;
                s_x[buf][c][r][col] = reg[i];
            }
        }
    };

    stage_load(0);                   // prologue
    int buf = 0;

    for (int ch = 0; ch < CINc / NCH; ++ch) {
        __syncthreads();             // prev compute on this buf done
        stage_store(buf);
        __syncthreads();             // staging visible

        if (ch < CINc / NCH - 1)
            stage_load(ch + 1);      // issue now; latency hidden by FMAs below

        #pragma unroll
        for (int c = 0; c < NCH; ++c) {
            float win[9];
            #pragma unroll
            for (int dy = 0; dy < 3; ++dy)
                #pragma unroll
                for (int dx = 0; dx < 3; ++dx)
                    win[dy * 3 + dx] = s_x[buf][c][ty + dy][w + dx];
            int cg = ch * NCH + c;
            #pragma unroll
            for (int oc = 0; oc < NOFF; ++oc) {
                const float* wp = w_off + ((size_t)oc * CINc + cg) * 9; // uniform -> s_load
                #pragma unroll
                for (int t = 0; t < 9; ++t)
                    acc[oc] += wp[t] * win[t];
            }
        }
        buf ^= 1;
    }

    int h = h0 + ty;
    #pragma unroll
    for (int oc = 0; oc < NOFF; ++oc)
        off[(((size_t)b * NOFF + oc) * Hn + h) * Wn + w] = acc[oc] + b_off[oc];
}

// ---------------------------------------------------------------------------
// Kernel B: bilinear sample + einsum (unchanged from round 1).
// ---------------------------------------------------------------------------
__global__ __launch_bounds__(256) void deform_main(
        const float* __restrict__ x, const float* __restrict__ off,
        const float* __restrict__ wt, float* __restrict__ out) {
    __shared__ float s_wts[KKc][64][4];     // masked bilinear weights
    __shared__ int   s_addr[KKc][64][4];    // clipped flat y*W+x per corner
    __shared__ float s_samp[CINc][68];      // sampled[c][p] for current k
    __shared__ float s_wk[CINc][68];        // w_def[k][c][o] for current k

    int gid = blockIdx.x;                   // 4*128*2 = 1024 blocks
    int wt2 = gid & 1;
    int h   = (gid >> 1) & (Hn - 1);
    int b   = gid >> 8;
    int w0  = wt2 * 64;
    int tid = threadIdx.x;

    // ---- phase 1: positions / weights for the 9*64 (k,p) pairs ----
    for (int j = tid; j < KKc * 64; j += 256) {
        int k = j >> 6, p = j & 63;
        float dy = off[(((size_t)b * NOFF + 2 * k) * Hn + h) * Wn + w0 + p];
        float dx = off[(((size_t)b * NOFF + 2 * k + 1) * Hn + h) * Wn + w0 + p];
        float py = (float)(h - 1 + k / 3) + dy;
        float px = (float)(w0 + p - 1 + k % 3) + dx;
        float y0f = floorf(py), x0f = floorf(px);
        float fy = py - y0f, fx = px - x0f;
        int y0 = (int)y0f, x0 = (int)x0f;
        int y1 = y0 + 1, x1 = x0 + 1;
        bool vy0 = (y0 >= 0) & (y0 < Hn);
        bool vy1 = (y1 >= 0) & (y1 < Hn);
        bool vx0 = (x0 >= 0) & (x0 < Wn);
        bool vx1 = (x1 >= 0) & (x1 < Wn);
        float wy0 = 1.f - fy, wx0 = 1.f - fx;
        s_wts[k][p][0] = (vy0 && vx0) ? wy0 * wx0 : 0.f;
        s_wts[k][p][1] = (vy0 && vx1) ? wy0 * fx : 0.f;
        s_wts[k][p][2] = (vy1 && vx0) ? fy * wx0 : 0.f;
        s_wts[k][p][3] = (vy1 && vx1) ? fy * fx : 0.f;
        int yc0 = min(max(y0, 0), Hn - 1), yc1 = min(max(y1, 0), Hn - 1);
        int xc0 = min(max(x0, 0), Wn - 1), xc1 = min(max(x1, 0), Wn - 1);
        s_addr[k][p][0] = yc0 * Wn + xc0;
        s_addr[k][p][1] = yc0 * Wn + xc1;
        s_addr[k][p][2] = yc1 * Wn + xc0;
        s_addr[k][p][3] = yc1 * Wn + xc1;
    }

    float acc[4][4] = {{0.f}};
    int p_g = tid & 63;           // staging: pixel
    int c_g = (tid >> 6) * 16;    // staging: channel base (16 channels each)
    int o0  = (tid >> 4) * 4;     // compute: o-tile
    int p0  = (tid & 15) * 4;     // compute: p-tile
    const float* xb = x + (size_t)b * CINc * Hn * Wn;

    for (int k = 0; k < KKc; ++k) {
        __syncthreads();   // phase1 done (k=0) / prev compute reads done (k>0)

        // ---- stage wk[c][o] (coalesced float4 from transposed w_def) ----
        const float* wk_src = wt + k * CINc * COUTc;
        #pragma unroll
        for (int i = 0; i < 4; ++i) {
            int idx = (i * 256 + tid) * 4;          // 0..4095, step 4
            int c = idx >> 6, o = idx & 63;
            float4 v = *(const float4*)(wk_src + idx);
            *(float4*)&s_wk[c][o] = v;
        }

        // ---- stage sampled[c][p] via bilinear gather ----
        int a0 = s_addr[k][p_g][0], a1 = s_addr[k][p_g][1];
        int a2 = s_addr[k][p_g][2], a3 = s_addr[k][p_g][3];
        float W0 = s_wts[k][p_g][0], W1 = s_wts[k][p_g][1];
        float W2 = s_wts[k][p_g][2], W3 = s_wts[k][p_g][3];
        #pragma unroll 4
        for (int i = 0; i < 16; ++i) {
            int c = c_g + i;
            const float* xc = xb + c * Hn * Wn;
            s_samp[c][p_g] = W0 * xc[a0] + W1 * xc[a1] + W2 * xc[a2] + W3 * xc[a3];
        }
        __syncthreads();

        // ---- 4x4 register-tile outer product over c ----
        #pragma unroll 8
        for (int c = 0; c < CINc; ++c) {
            float4 wv = *(float4*)&s_wk[c][o0];
            float4 sv = *(float4*)&s_samp[c][p0];
            float wa[4] = {wv.x, wv.y, wv.z, wv.w};
            float sa[4] = {sv.x, sv.y, sv.z, sv.w};
            #pragma unroll
            for (int i = 0; i < 4; ++i)
                #pragma unroll
                for (int j = 0; j < 4; ++j)
                    acc[i][j] += wa[i] * sa[j];
        }
    }

    // ---- write out: 4 rows of float4 ----
    #pragma unroll
    for (int i = 0; i < 4; ++i) {
        float4 v = make_float4(acc[i][0], acc[i][1], acc[i][2], acc[i][3]);
        *(float4*)(out + (((size_t)b * COUTc + o0 + i) * Hn + h) * Wn + w0 + p0) = v;
    }
}

// ---------------------------------------------------------------------------
extern "C" void kernel_launch(void* const* d_in, const int* in_sizes, int n_in,
                              void* d_out, int out_size, void* d_ws, size_t ws_size,
                              hipStream_t stream) {
    const float* x     = (const float*)d_in[0];
    const float* w_off = (const float*)d_in[1];
    const float* b_off = (const float*)d_in[2];
    const float* w_def = (const float*)d_in[3];
    float* out = (float*)d_out;

    float* off = (float*)d_ws;                                   // 4*18*128*128 fp32
    float* wtp = (float*)((char*)d_ws + (size_t)Bn * NOFF * Hn * Wn * 4);

    transpose_wdef<<<(COUTc * CINc * KKc + 255) / 256, 256, 0, stream>>>(w_def, wtp);
    offset_conv_v2<<<Bn * 64, 256, 0, stream>>>(x, w_off, b_off, off);
    deform_main<<<Bn * Hn * (Wn / 64), 256, 0, stream>>>(x, off, wtp, out);
}

// Round 3
// 255.687 us; speedup vs baseline: 1.5980x; 1.1658x over previous
//
#include <hip/hip_runtime.h>

#define Bn   4
#define CINc 64
#define COUTc 64
#define Hn   128
#define Wn   128
#define KKc  9
#define NOFF 18

typedef short bf16x8 __attribute__((ext_vector_type(8)));
typedef float f32x4  __attribute__((ext_vector_type(4)));

__device__ inline unsigned short f2bf(float f) {   // RNE fp32 -> bf16
    unsigned int u = __float_as_uint(f);
    return (unsigned short)((u + 0x7fffu + ((u >> 16) & 1u)) >> 16);
}

// ---------------------------------------------------------------------------
// prep: wkb[k][o][c] (bf16)  <-  w_def[o][c][k] (fp32)
// ---------------------------------------------------------------------------
__global__ void prep_wdef(const float* __restrict__ w_def,
                          unsigned short* __restrict__ wkb) {
    int idx = blockIdx.x * 256 + threadIdx.x;          // o*576 + c*9 + k
    if (idx >= COUTc * CINc * KKc) return;
    int k = idx % 9;
    int c = (idx / 9) % 64;
    int o = idx / 576;
    wkb[((size_t)k * 64 + o) * 64 + c] = f2bf(w_def[idx]);
}

// ---------------------------------------------------------------------------
// offset conv v3: block = (b, h) -> 512 blocks, 256 threads.
// waves {0,1} handle channels 0..31, waves {2,3} handle 32..63 (cp from
// readfirstlane so weight addresses stay scalar -> s_load). Per-half LDS
// staging of 8-channel chunks [8][3 rows][132 cols]; LDS reduce across the
// two halves at the end. 2 blocks/CU, 8 waves/CU.
// ---------------------------------------------------------------------------
__global__ __launch_bounds__(256, 2) void offset_conv_v3(
        const float* __restrict__ x, const float* __restrict__ w_off,
        const float* __restrict__ b_off, float* __restrict__ off) {
    __shared__ float s_x[2][8][3][132];    // 25.3 KB
    __shared__ float s_red[NOFF][128];     //  9.2 KB

    int bid = blockIdx.x;                  // 512
    int h   = bid & 127;
    int b   = bid >> 7;
    int tid = threadIdx.x;
    int lane = tid & 63;
    int wave = __builtin_amdgcn_readfirstlane(tid >> 6);
    int cp   = wave >> 1;                  // scalar: which 32-channel half
    int px   = lane + (wave & 1) * 64;     // pixel col 0..127

    const float* xb = x + (size_t)b * CINc * Hn * Wn;

    float acc[NOFF];
    #pragma unroll
    for (int i = 0; i < NOFF; ++i) acc[i] = 0.f;

    float reg[25];
    auto stage_load = [&](int chunk) {     // 3168 elems over 128 threads
        int cbase = cp * 32 + chunk * 8;
        #pragma unroll
        for (int i = 0; i < 25; ++i) {
            int idx = px + i * 128;
            if (idx < 3168) {
                int c   = idx / 396;
                int rem = idx - c * 396;
                int r   = rem / 132;
                int col = rem - r * 132;
                int y   = h - 1 + r;
                int xg  = col - 1;
                float v = 0.f;
                if (y >= 0 && y < Hn && xg >= 0 && xg < Wn)
                    v = xb[((size_t)(cbase + c) * Hn + y) * Wn + xg];
                reg[i] = v;
            }
        }
    };
    auto stage_store = [&]() {
        #pragma unroll
        for (int i = 0; i < 25; ++i) {
            int idx = px + i * 128;
            if (idx < 3168) {
                int c   = idx / 396;
                int rem = idx - c * 396;
                int r   = rem / 132;
                int col = rem - r * 132;
                s_x[cp][c][r][col] = reg[i];
            }
        }
    };

    stage_load(0);
    for (int ch = 0; ch < 4; ++ch) {
        __syncthreads();                   // prev compute done reading s_x
        stage_store();
        __syncthreads();                   // staging visible
        if (ch < 3) stage_load(ch + 1);    // overlap with FMAs below

        int cbase = cp * 32 + ch * 8;
        #pragma unroll
        for (int c = 0; c < 8; ++c) {
            float win[9];
            #pragma unroll
            for (int dy = 0; dy < 3; ++dy)
                #pragma unroll
                for (int dx = 0; dx < 3; ++dx)
                    win[dy * 3 + dx] = s_x[cp][c][dy][px + dx];
            #pragma unroll
            for (int oc = 0; oc < NOFF; ++oc) {
                const float* wp = w_off + ((size_t)oc * CINc + cbase + c) * 9;
                #pragma unroll
                for (int t = 0; t < 9; ++t)
                    acc[oc] += wp[t] * win[t];
            }
        }
    }

    // reduce halves, add bias, write
    __syncthreads();
    if (cp == 1) {
        #pragma unroll
        for (int oc = 0; oc < NOFF; ++oc) s_red[oc][px] = acc[oc];
    }
    __syncthreads();
    if (cp == 0) {
        #pragma unroll
        for (int oc = 0; oc < NOFF; ++oc) {
            float v = acc[oc] + s_red[oc][px] + b_off[oc];
            off[(((size_t)b * NOFF + oc) * Hn + h) * Wn + px] = v;
        }
    }
}

// ---------------------------------------------------------------------------
// deform main v3: bilinear sample + bf16-MFMA einsum.
// Grid 1024, XCD-swizzled: blockIdx&7 selects a 16-row h band so each XCD's
// x working set (~2.4 MB) stays L2-resident.
// Per k: gather+blend -> packed bf16 S_T[p][c] in LDS (row stride 33 dwords
// -> 2-way-free banks), W frags loaded per-k from wkb[k][o][c] (L1-hot),
// 8x mfma_f32_16x16x32_bf16 per wave (o-strip 16, 4 p-tiles, K=64).
// ---------------------------------------------------------------------------
__global__ __launch_bounds__(256, 4) void deform_main_v3(
        const float* __restrict__ x, const float* __restrict__ off,
        const unsigned short* __restrict__ wkb, float* __restrict__ out) {
    __shared__ int          s_addr[KKc][64][4];
    __shared__ float        s_wts[KKc][64][4];
    __shared__ unsigned int s_st[64][33];   // S_T[p][c/2] bf16x2

    int gid  = blockIdx.x;                  // 1024
    int xcd  = gid & 7;
    int j    = gid >> 3;                    // 0..127
    int half = j & 1;
    int hh   = (j >> 1) & 15;
    int b    = (j >> 5) & 3;
    int h    = xcd * 16 + hh;
    int w0   = half * 64;
    int tid  = threadIdx.x;
    int lane = tid & 63;
    int wave = __builtin_amdgcn_readfirstlane(tid >> 6);
    int l15  = lane & 15;
    int quad = lane >> 4;
    int o_base = wave * 16;

    // ---- phase 1: bilinear addresses + masked weights for 9*64 (k,p) ----
    for (int jj = tid; jj < KKc * 64; jj += 256) {
        int k = jj >> 6, p = jj & 63;
        float dy = off[(((size_t)b * NOFF + 2 * k) * Hn + h) * Wn + w0 + p];
        float dx = off[(((size_t)b * NOFF + 2 * k + 1) * Hn + h) * Wn + w0 + p];
        float py = (float)(h - 1 + k / 3) + dy;
        float px = (float)(w0 + p - 1 + k % 3) + dx;
        float y0f = floorf(py), x0f = floorf(px);
        float fy = py - y0f, fx = px - x0f;
        int y0 = (int)y0f, x0 = (int)x0f;
        int y1 = y0 + 1, x1 = x0 + 1;
        bool vy0 = (y0 >= 0) & (y0 < Hn);
        bool vy1 = (y1 >= 0) & (y1 < Hn);
        bool vx0 = (x0 >= 0) & (x0 < Wn);
        bool vx1 = (x1 >= 0) & (x1 < Wn);
        float wy0 = 1.f - fy, wx0 = 1.f - fx;
        s_wts[k][p][0] = (vy0 && vx0) ? wy0 * wx0 : 0.f;
        s_wts[k][p][1] = (vy0 && vx1) ? wy0 * fx  : 0.f;
        s_wts[k][p][2] = (vy1 && vx0) ? fy  * wx0 : 0.f;
        s_wts[k][p][3] = (vy1 && vx1) ? fy  * fx  : 0.f;
        int yc0 = min(max(y0, 0), Hn - 1), yc1 = min(max(y1, 0), Hn - 1);
        int xc0 = min(max(x0, 0), Wn - 1), xc1 = min(max(x1, 0), Wn - 1);
        s_addr[k][p][0] = yc0 * Wn + xc0;
        s_addr[k][p][1] = yc0 * Wn + xc1;
        s_addr[k][p][2] = yc1 * Wn + xc0;
        s_addr[k][p][3] = yc1 * Wn + xc1;
    }

    f32x4 acc[4];
    #pragma unroll
    for (int pt = 0; pt < 4; ++pt) acc[pt] = (f32x4){0.f, 0.f, 0.f, 0.f};

    int p_g = lane;                 // staging: this thread's pixel
    int cg  = wave * 16;            // staging: channel base (16 ch per wave)
    const float* xb = x + (size_t)b * CINc * Hn * Wn;
    const bf16x8* wk8 = (const bf16x8*)wkb;

    for (int k = 0; k < KKc; ++k) {
        __syncthreads();            // phase1 done / prev MFMA reads done

        // per-k A frags (W[o][c]), same for all blocks -> L1-hot
        bf16x8 af0 = wk8[(((size_t)k * 64 + o_base + l15) * 64 +      quad * 8) >> 3];
        bf16x8 af1 = wk8[(((size_t)k * 64 + o_base + l15) * 64 + 32 + quad * 8) >> 3];

        // ---- stage S_T[p][c] bf16 (2 channels per dword write) ----
        int a0 = s_addr[k][p_g][0], a1 = s_addr[k][p_g][1];
        int a2 = s_addr[k][p_g][2], a3 = s_addr[k][p_g][3];
        float W0 = s_wts[k][p_g][0], W1 = s_wts[k][p_g][1];
        float W2 = s_wts[k][p_g][2], W3 = s_wts[k][p_g][3];
        #pragma unroll
        for (int i = 0; i < 8; ++i) {
            int c0 = cg + 2 * i;
            const float* xc0 = xb + (size_t)c0 * (Hn * Wn);
            const float* xc1 = xc0 + Hn * Wn;
            float v0 = W0 * xc0[a0] + W1 * xc0[a1] + W2 * xc0[a2] + W3 * xc0[a3];
            float v1 = W0 * xc1[a0] + W1 * xc1[a1] + W2 * xc1[a2] + W3 * xc1[a3];
            s_st[p_g][c0 >> 1] = (unsigned)f2bf(v0) | ((unsigned)f2bf(v1) << 16);
        }
        __syncthreads();

        // ---- MFMA: D[o][p] += W[o][c] * S[c][p], K=64 in 2 chunks ----
        #pragma unroll
        for (int kc = 0; kc < 2; ++kc) {
            bf16x8 af = kc ? af1 : af0;
            #pragma unroll
            for (int pt = 0; pt < 4; ++pt) {
                int p = pt * 16 + l15;
                union { bf16x8 v; unsigned u[4]; } bf;
                int base = kc * 16 + quad * 4;
                bf.u[0] = s_st[p][base + 0];
                bf.u[1] = s_st[p][base + 1];
                bf.u[2] = s_st[p][base + 2];
                bf.u[3] = s_st[p][base + 3];
                acc[pt] = __builtin_amdgcn_mfma_f32_16x16x32_bf16(af, bf.v, acc[pt], 0, 0, 0);
            }
        }
    }

    // ---- epilogue: C/D layout col=lane&15 (=p), row=quad*4+reg (=o) ----
    #pragma unroll
    for (int pt = 0; pt < 4; ++pt)
        #pragma unroll
        for (int r = 0; r < 4; ++r) {
            int o = o_base + quad * 4 + r;
            int p = pt * 16 + l15;
            out[(((size_t)b * COUTc + o) * Hn + h) * Wn + w0 + p] = acc[pt][r];
        }
}

// ---------------------------------------------------------------------------
extern "C" void kernel_launch(void* const* d_in, const int* in_sizes, int n_in,
                              void* d_out, int out_size, void* d_ws, size_t ws_size,
                              hipStream_t stream) {
    const float* x     = (const float*)d_in[0];
    const float* w_off = (const float*)d_in[1];
    const float* b_off = (const float*)d_in[2];
    const float* w_def = (const float*)d_in[3];
    float* out = (float*)d_out;

    float* off = (float*)d_ws;  // 4*18*128*128 fp32 = 4.72 MB
    unsigned short* wkb = (unsigned short*)((char*)d_ws +
                          (size_t)Bn * NOFF * Hn * Wn * sizeof(float));

    prep_wdef<<<(COUTc * CINc * KKc + 255) / 256, 256, 0, stream>>>(w_def, wkb);
    offset_conv_v3<<<Bn * Hn, 256, 0, stream>>>(x, w_off, b_off, off);
    deform_main_v3<<<Bn * Hn * (Wn / 64), 256, 0, stream>>>(x, off, wkb, out);
}

// Round 4
// 157.026 us; speedup vs baseline: 2.6020x; 1.6283x over previous
//
#include <hip/hip_runtime.h>

#define Bn   4
#define CINc 64
#define COUTc 64
#define Hn   128
#define Wn   128
#define HW   (Hn * Wn)
#define KKc  9
#define NOFF 18

typedef short bf16x8 __attribute__((ext_vector_type(8)));
typedef float f32x4  __attribute__((ext_vector_type(4)));

__device__ inline unsigned short f2bf(float f) {   // RNE fp32 -> bf16
    unsigned int u = __float_as_uint(f);
    return (unsigned short)((u + 0x7fffu + ((u >> 16) & 1u)) >> 16);
}

// ---------------------------------------------------------------------------
// prep: wkb[k][o][c] bf16 <- w_def[o][c][k] ; wob[t][m(32,pad)][c] bf16 <- w_off
// ---------------------------------------------------------------------------
__global__ void prep_weights(const float* __restrict__ w_off,
                             const float* __restrict__ w_def,
                             unsigned short* __restrict__ wkb,
                             unsigned short* __restrict__ wob) {
    int idx = blockIdx.x * 256 + threadIdx.x;
    if (idx < COUTc * CINc * KKc) {                 // 36864
        int k = idx % 9;
        int c = (idx / 9) % 64;
        int o = idx / 576;
        wkb[((size_t)k * 64 + o) * 64 + c] = f2bf(w_def[idx]);
    }
    int j = idx - COUTc * CINc * KKc;
    if (j >= 0 && j < KKc * 32 * CINc) {            // 18432: wob[t<<11|m<<6|c]
        int c = j & 63, m = (j >> 6) & 31, t = j >> 11;
        unsigned short v = 0;
        if (m < NOFF) v = f2bf(w_off[((size_t)m * 64 + c) * 9 + t]);
        wob[j] = v;
    }
}

// ---------------------------------------------------------------------------
// offset conv v4: tap-decomposed MFMA GEMM. Block = (b,h) (XCD-swizzled),
// 256 thr. Stage xT[3 rows][132 cols][64 c] bf16 in LDS (col stride 33 dw ->
// conflict-free), ONE barrier, then per tap t=(ty,tx): B-frag = 16B of
// channels at col p+tx, A-frag = wob[t][octile][c] (L1-hot).
// off[oc 0..17][p] via 2 oc-tiles (16..31 padded with zero weights).
// ---------------------------------------------------------------------------
__global__ __launch_bounds__(256, 2) void offset_conv_v4(
        const float* __restrict__ x, const unsigned short* __restrict__ wob,
        const float* __restrict__ b_off, float* __restrict__ off) {
    __shared__ unsigned s_xt[3][132][33];   // [row][col=x+1][c-pair] 52.3 KB

    int bid = blockIdx.x;                   // 512
    int xcd = bid & 7;
    int j   = bid >> 3;                     // 0..63
    int hh  = j & 15;
    int b   = j >> 4;
    int h   = xcd * 16 + hh;
    int tid = threadIdx.x;
    int lane = tid & 63;
    int wave = __builtin_amdgcn_readfirstlane(tid >> 6);
    int l15 = lane & 15, quad = lane >> 4;

    const float* xb = x + (size_t)b * CINc * HW;

    // zero halo cols 0 (x=-1) and 129 (x=128)
    if (tid < 198) {
        int r = tid / 66, rem = tid % 66;
        int col = (rem >= 33) ? 129 : 0;
        s_xt[r][col][rem % 33] = 0;
    }
    // stage: wave handles 16 channels, lane = col
    for (int r = 0; r < 3; ++r) {
        int y = h - 1 + r;
        if (y >= 0 && y < Hn) {
            #pragma unroll
            for (int half = 0; half < 2; ++half) {
                int xcol = lane + half * 64;
                const float* base = xb + (size_t)y * Wn + xcol;
                #pragma unroll
                for (int i = 0; i < 8; ++i) {
                    int c = wave * 16 + 2 * i;
                    float v0 = base[(size_t)c * HW];
                    float v1 = base[(size_t)(c + 1) * HW];
                    s_xt[r][xcol + 1][wave * 8 + i] =
                        (unsigned)f2bf(v0) | ((unsigned)f2bf(v1) << 16);
                }
            }
        } else {
            #pragma unroll
            for (int half = 0; half < 2; ++half) {
                int xcol = lane + half * 64;
                #pragma unroll
                for (int i = 0; i < 8; ++i)
                    s_xt[r][xcol + 1][wave * 8 + i] = 0;
            }
        }
    }
    __syncthreads();

    f32x4 acc[2][2];
    #pragma unroll
    for (int ot = 0; ot < 2; ++ot)
        #pragma unroll
        for (int pt = 0; pt < 2; ++pt) acc[ot][pt] = (f32x4){0.f, 0.f, 0.f, 0.f};

    #pragma unroll
    for (int t = 0; t < 9; ++t) {
        int ty = t / 3, tx = t % 3;
        #pragma unroll
        for (int kc = 0; kc < 2; ++kc) {
            bf16x8 a0 = *(const bf16x8*)(wob + ((t * 32 + l15) * 64 + kc * 32 + quad * 8));
            bf16x8 a1 = *(const bf16x8*)(wob + ((t * 32 + 16 + l15) * 64 + kc * 32 + quad * 8));
            #pragma unroll
            for (int pt = 0; pt < 2; ++pt) {
                int col = (wave * 2 + pt) * 16 + l15 + tx;
                const unsigned* bp = &s_xt[ty][col][kc * 16 + quad * 4];
                union { bf16x8 v; unsigned u[4]; } bf;
                bf.u[0] = bp[0]; bf.u[1] = bp[1]; bf.u[2] = bp[2]; bf.u[3] = bp[3];
                acc[0][pt] = __builtin_amdgcn_mfma_f32_16x16x32_bf16(a0, bf.v, acc[0][pt], 0, 0, 0);
                acc[1][pt] = __builtin_amdgcn_mfma_f32_16x16x32_bf16(a1, bf.v, acc[1][pt], 0, 0, 0);
            }
        }
    }

    // epilogue: C layout col=l15 (=p within tile), row=quad*4+r (=oc)
    #pragma unroll
    for (int pt = 0; pt < 2; ++pt) {
        int p = (wave * 2 + pt) * 16 + l15;
        #pragma unroll
        for (int r = 0; r < 4; ++r) {
            int oc = quad * 4 + r;
            off[(((size_t)b * NOFF + oc) * Hn + h) * Wn + p] = acc[0][pt][r] + b_off[oc];
        }
        if (quad == 0) {
            #pragma unroll
            for (int r = 0; r < 2; ++r) {
                int oc = 16 + r;
                off[(((size_t)b * NOFF + oc) * Hn + h) * Wn + p] = acc[1][pt][r] + b_off[oc];
            }
        }
    }
}

// ---------------------------------------------------------------------------
// deform main v4: pair-load gather + bf16 MFMA einsum.
// Phase 1 folds x-clipping into 4 weights per (k,p) and 2 row-base addrs;
// gather is 2 float2 loads per (channel,row-pair) — half the v3 instr count.
// ---------------------------------------------------------------------------
__global__ __launch_bounds__(256, 4) void deform_main_v4(
        const float* __restrict__ x, const float* __restrict__ off,
        const unsigned short* __restrict__ wkb, float* __restrict__ out) {
    __shared__ int          s_ad[KKc][64][2];   // {yc0*W+xc, yc1*W+xc}
    __shared__ float4       s_w4[KKc][64];      // folded corner weights
    __shared__ unsigned int s_st[64][33];       // S_T[p][c/2] bf16x2

    int gid  = blockIdx.x;                  // 1024
    int xcd  = gid & 7;
    int j    = gid >> 3;
    int half = j & 1;
    int hh   = (j >> 1) & 15;
    int b    = (j >> 5) & 3;
    int h    = xcd * 16 + hh;
    int w0   = half * 64;
    int tid  = threadIdx.x;
    int lane = tid & 63;
    int wave = __builtin_amdgcn_readfirstlane(tid >> 6);
    int l15  = lane & 15;
    int quad = lane >> 4;
    int o_base = wave * 16;

    // ---- phase 1 ----
    for (int jj = tid; jj < KKc * 64; jj += 256) {
        int k = jj >> 6, p = jj & 63;
        float dy = off[(((size_t)b * NOFF + 2 * k) * Hn + h) * Wn + w0 + p];
        float dx = off[(((size_t)b * NOFF + 2 * k + 1) * Hn + h) * Wn + w0 + p];
        float py = (float)(h - 1 + k / 3) + dy;
        float px = (float)(w0 + p - 1 + k % 3) + dx;
        float y0f = floorf(py), x0f = floorf(px);
        float fy = py - y0f, fx = px - x0f;
        int y0 = (int)y0f, x0 = (int)x0f;
        bool vy0 = (y0 >= 0) & (y0 < Hn);
        bool vy1 = (y0 + 1 >= 0) & (y0 + 1 < Hn);
        bool vx0 = (x0 >= 0) & (x0 < Wn);
        bool vx1 = (x0 + 1 >= 0) & (x0 + 1 < Wn);
        float wy0 = vy0 ? 1.f - fy : 0.f;
        float wy1 = vy1 ? fy : 0.f;
        float wx0 = vx0 ? 1.f - fx : 0.f;
        float wx1 = vx1 ? fx : 0.f;
        int xc = min(max(x0, 0), Wn - 2);           // pair base (may be odd)
        // fold clip-selects into pair weights: slot0 = xc, slot1 = xc+1
        bool sel0 = (min(max(x0, 0), Wn - 1) != xc);          // corner0 -> slot1
        bool sel1 = ((min(max(x0 + 1, 0), Wn - 1) - xc) == 1); // corner1 -> slot1
        float Wa = (sel0 ? 0.f : wx0) + (sel1 ? 0.f : wx1);
        float Wb = (sel0 ? wx0 : 0.f) + (sel1 ? wx1 : 0.f);
        int yc0 = min(max(y0, 0), Hn - 1), yc1 = min(max(y0 + 1, 0), Hn - 1);
        s_ad[k][p][0] = yc0 * Wn + xc;
        s_ad[k][p][1] = yc1 * Wn + xc;
        s_w4[k][p] = make_float4(wy0 * Wa, wy0 * Wb, wy1 * Wa, wy1 * Wb);
    }

    f32x4 acc[4];
    #pragma unroll
    for (int pt = 0; pt < 4; ++pt) acc[pt] = (f32x4){0.f, 0.f, 0.f, 0.f};

    int p_g = lane;
    int cg  = wave * 16;
    const float* xb = x + (size_t)b * CINc * HW;
    const bf16x8* wk8 = (const bf16x8*)wkb;

    for (int k = 0; k < KKc; ++k) {
        __syncthreads();

        bf16x8 af0 = wk8[(((size_t)k * 64 + o_base + l15) * 64 +      quad * 8) >> 3];
        bf16x8 af1 = wk8[(((size_t)k * 64 + o_base + l15) * 64 + 32 + quad * 8) >> 3];

        int a_top = s_ad[k][p_g][0];
        int a_bot = s_ad[k][p_g][1];
        float4 Wv = s_w4[k][p_g];
        #pragma unroll
        for (int i = 0; i < 8; ++i) {
            int c0 = cg + 2 * i;
            const float* x0p = xb + (size_t)c0 * HW;
            const float* x1p = x0p + HW;
            float2 t0 = *(const float2*)(x0p + a_top);
            float2 b0 = *(const float2*)(x0p + a_bot);
            float2 t1 = *(const float2*)(x1p + a_top);
            float2 b1 = *(const float2*)(x1p + a_bot);
            float v0 = Wv.x * t0.x + Wv.y * t0.y + Wv.z * b0.x + Wv.w * b0.y;
            float v1 = Wv.x * t1.x + Wv.y * t1.y + Wv.z * b1.x + Wv.w * b1.y;
            s_st[p_g][c0 >> 1] = (unsigned)f2bf(v0) | ((unsigned)f2bf(v1) << 16);
        }
        __syncthreads();

        #pragma unroll
        for (int kc = 0; kc < 2; ++kc) {
            bf16x8 af = kc ? af1 : af0;
            #pragma unroll
            for (int pt = 0; pt < 4; ++pt) {
                int p = pt * 16 + l15;
                union { bf16x8 v; unsigned u[4]; } bf;
                int base = kc * 16 + quad * 4;
                bf.u[0] = s_st[p][base + 0];
                bf.u[1] = s_st[p][base + 1];
                bf.u[2] = s_st[p][base + 2];
                bf.u[3] = s_st[p][base + 3];
                acc[pt] = __builtin_amdgcn_mfma_f32_16x16x32_bf16(af, bf.v, acc[pt], 0, 0, 0);
            }
        }
    }

    #pragma unroll
    for (int pt = 0; pt < 4; ++pt)
        #pragma unroll
        for (int r = 0; r < 4; ++r) {
            int o = o_base + quad * 4 + r;
            int p = pt * 16 + l15;
            out[(((size_t)b * COUTc + o) * Hn + h) * Wn + w0 + p] = acc[pt][r];
        }
}

// ---------------------------------------------------------------------------
extern "C" void kernel_launch(void* const* d_in, const int* in_sizes, int n_in,
                              void* d_out, int out_size, void* d_ws, size_t ws_size,
                              hipStream_t stream) {
    const float* x     = (const float*)d_in[0];
    const float* w_off = (const float*)d_in[1];
    const float* b_off = (const float*)d_in[2];
    const float* w_def = (const float*)d_in[3];
    float* out = (float*)d_out;

    char* ws = (char*)d_ws;
    float* off = (float*)ws;                                  // 4.72 MB
    ws += (size_t)Bn * NOFF * Hn * Wn * sizeof(float);
    unsigned short* wkb = (unsigned short*)ws;                // 73728 B
    ws += (size_t)KKc * COUTc * CINc * sizeof(unsigned short);
    unsigned short* wob = (unsigned short*)ws;                // 36864 B

    prep_weights<<<216, 256, 0, stream>>>(w_off, w_def, wkb, wob);
    offset_conv_v4<<<Bn * Hn, 256, 0, stream>>>(x, wob, b_off, off);
    deform_main_v4<<<Bn * Hn * (Wn / 64), 256, 0, stream>>>(x, off, wkb, out);
}